// Round 2
// baseline (453.906 us; speedup 1.0000x reference)
//
#include <hip/hip_runtime.h>
#include <math.h>

#define HH 1536
#define WW 1536
#define HWN (HH*WW)
#define CC 16
#define KSZ 5
#define PS 17

// ---------------- reduction helpers ----------------
__device__ inline float waveMax(float v) {
#pragma unroll
  for (int o = 32; o; o >>= 1) v = fmaxf(v, __shfl_xor(v, o));
  return v;
}
__device__ inline float waveSum(float v) {
#pragma unroll
  for (int o = 32; o; o >>= 1) v += __shfl_xor(v, o);
  return v;
}

__device__ inline float softplusf(float x) {
  return x > 20.f ? x : log1pf(expf(x));
}

// ---------------- K1: content score s = beta_pos * cos_sim ----------------
__global__ void k_score(const float* __restrict__ mem, const float* __restrict__ key,
                        const float* __restrict__ beta, float* __restrict__ sbuf,
                        float* __restrict__ red) {
  __shared__ float sm[4];
  float kv[CC];
  float kn = 0.f;
#pragma unroll
  for (int c = 0; c < CC; c++) { kv[c] = key[c]; kn += kv[c] * kv[c]; }
  kn = fmaxf(sqrtf(kn), 1e-8f);
  float scale = softplusf(beta[0]) / kn;

  float lmax = -INFINITY;
  int stride = gridDim.x * blockDim.x;
  for (int hw = blockIdx.x * blockDim.x + threadIdx.x; hw < HWN; hw += stride) {
    float dot = 0.f, nrm = 0.f;
#pragma unroll
    for (int c = 0; c < CC; c++) {
      float m = mem[c * HWN + hw];
      dot += m * kv[c];
      nrm += m * m;
    }
    float s = scale * dot / fmaxf(sqrtf(nrm), 1e-8f);
    sbuf[hw] = s;
    lmax = fmaxf(lmax, s);
  }
  lmax = waveMax(lmax);
  if ((threadIdx.x & 63) == 0) sm[threadIdx.x >> 6] = lmax;
  __syncthreads();
  if (threadIdx.x == 0) {
    float m = sm[0];
    for (int i = 1; i < 4; i++) m = fmaxf(m, sm[i]);
    red[blockIdx.x] = m;
  }
}

// ---------------- K2: reduce max over 2048 partials; shift-kernel softmax ----------------
__global__ void k_redmax(const float* __restrict__ red, float* __restrict__ scal,
                         const float* __restrict__ shift, float* __restrict__ skb) {
  __shared__ float sm[256];
  float m = -INFINITY;
  for (int i = threadIdx.x; i < 2048; i += 256) m = fmaxf(m, red[i]);
  sm[threadIdx.x] = m;
  __syncthreads();
  for (int s = 128; s; s >>= 1) {
    if (threadIdx.x < s) sm[threadIdx.x] = fmaxf(sm[threadIdx.x], sm[threadIdx.x + s]);
    __syncthreads();
  }
  if (threadIdx.x == 0) {
    scal[0] = sm[0];
    float mx = -INFINITY;
    for (int i = 0; i < KSZ * KSZ; i++) mx = fmaxf(mx, shift[i]);
    float e[KSZ * KSZ];
    float sum = 0.f;
    for (int i = 0; i < KSZ * KSZ; i++) { e[i] = expf(shift[i] - mx); sum += e[i]; }
    for (int i = 0; i < KSZ * KSZ; i++) skb[i] = e[i] / sum;
  }
}

// ---------------- K3: e = exp(s - M), partial sums ----------------
__global__ void k_exp(float* __restrict__ sbuf, const float* __restrict__ scal,
                      float* __restrict__ red) {
  __shared__ float sm[4];
  float M = scal[0];
  float lsum = 0.f;
  int stride = gridDim.x * blockDim.x;
  for (int hw = blockIdx.x * blockDim.x + threadIdx.x; hw < HWN; hw += stride) {
    float e = expf(sbuf[hw] - M);
    sbuf[hw] = e;
    lsum += e;
  }
  lsum = waveSum(lsum);
  if ((threadIdx.x & 63) == 0) sm[threadIdx.x >> 6] = lsum;
  __syncthreads();
  if (threadIdx.x == 0) red[blockIdx.x] = sm[0] + sm[1] + sm[2] + sm[3];
}

// ---------------- K4: reduce sum over partials ----------------
__global__ void k_redsum(const float* __restrict__ red, float* __restrict__ scal,
                         int n, int slot) {
  __shared__ float sm[256];
  float s = 0.f;
  for (int i = threadIdx.x; i < n; i += 256) s += red[i];
  sm[threadIdx.x] = s;
  __syncthreads();
  for (int st = 128; st; st >>= 1) {
    if (threadIdx.x < st) sm[threadIdx.x] += sm[threadIdx.x + st];
    __syncthreads();
  }
  if (threadIdx.x == 0) {
    if (slot == 1) scal[1] = sm[0];
    else scal[2] = 1.f / fmaxf(sm[0], 1e-6f);   // invS2 for final normalization
  }
}

// ---------------- K5: w_g = g*e/S + (1-g)*prev ----------------
__global__ void k_wg(const float* __restrict__ e, const float* __restrict__ prev,
                     const float* __restrict__ scal, const float* __restrict__ gate,
                     float* __restrict__ wg) {
  float invS = 1.f / scal[1];
  float g = 1.f / (1.f + expf(-gate[0]));
  float og = 1.f - g;
  int stride = gridDim.x * blockDim.x;
  for (int hw = blockIdx.x * blockDim.x + threadIdx.x; hw < HWN; hw += stride) {
    wg[hw] = g * e[hw] * invS + og * prev[hw];
  }
}

// ---------------- K6: 5x5 circular conv + pow(zeta), partial sums ----------------
__global__ void k_shift(const float* __restrict__ wg, const float* __restrict__ skb,
                        const float* __restrict__ sharpen, float* __restrict__ t,
                        float* __restrict__ red) {
  __shared__ float tile[20][21];
  __shared__ float sks[KSZ * KSZ];
  __shared__ float sm[4];
  int tx = threadIdx.x & 15, ty = threadIdx.x >> 4;
  int x0 = blockIdx.x * 16, y0 = blockIdx.y * 16;
  if (threadIdx.x < KSZ * KSZ) sks[threadIdx.x] = skb[threadIdx.x];
  for (int i = threadIdx.x; i < 400; i += 256) {
    int r = i / 20, c = i % 20;
    int gy = (y0 + r - 2 + HH) % HH;
    int gx = (x0 + c - 2 + WW) % WW;
    tile[r][c] = wg[gy * WW + gx];
  }
  __syncthreads();
  float zeta = softplusf(sharpen[0]) + 1.f;
  float acc = 0.f;
#pragma unroll
  for (int i = 0; i < KSZ; i++)
#pragma unroll
    for (int j = 0; j < KSZ; j++)
      acc += sks[i * KSZ + j] * tile[ty + i][tx + j];
  float tp = powf(fmaxf(acc, 1e-8f), zeta);
  t[(y0 + ty) * WW + x0 + tx] = tp;
  float lsum = waveSum(tp);
  if ((threadIdx.x & 63) == 0) sm[threadIdx.x >> 6] = lsum;
  __syncthreads();
  if (threadIdx.x == 0) red[blockIdx.y * 96 + blockIdx.x] = sm[0] + sm[1] + sm[2] + sm[3];
}

// ---------------- K8: 17x17 true conv of weights with patch + mem add ----------------
__global__ void __launch_bounds__(256) k_conv17(
    const float* __restrict__ t, const float* __restrict__ scal,
    const float* __restrict__ patch, const float* __restrict__ mem,
    float* __restrict__ out) {
  __shared__ __align__(16) float wl[32][36];
  int c = threadIdx.x & 15;
  int strip = threadIdx.x >> 4;
  int x0 = blockIdx.x * 16, y0 = blockIdx.y * 16;
  float invS = scal[2];
  for (int i = threadIdx.x; i < 1024; i += 256) {
    int r = i >> 5, cc = i & 31;
    int gy = y0 - 8 + r, gx = x0 - 8 + cc;
    float v = 0.f;
    if (gy >= 0 && gy < HH && gx >= 0 && gx < WW) v = t[gy * WW + gx] * invS;
    wl[r][cc] = v;
  }
  __syncthreads();

  float acc[16];
#pragma unroll
  for (int i = 0; i < 16; i++) acc[i] = 0.f;
  const float* pr = patch + c * (PS * PS);

#pragma unroll 1
  for (int u = 0; u < PS; u++) {
    float p[PS];
#pragma unroll
    for (int v = 0; v < PS; v++) p[v] = pr[u * PS + v];
    int row = strip + 16 - u;
    float wr[32];
#pragma unroll
    for (int i = 0; i < 8; i++) {
      float4 q = *reinterpret_cast<const float4*>(&wl[row][i * 4]);
      wr[i * 4 + 0] = q.x; wr[i * 4 + 1] = q.y; wr[i * 4 + 2] = q.z; wr[i * 4 + 3] = q.w;
    }
#pragma unroll
    for (int v = 0; v < PS; v++)
#pragma unroll
      for (int sx = 0; sx < 16; sx++)
        acc[sx] += wr[sx + 16 - v] * p[v];
  }

  int y = y0 + strip;
  const float* mrow = mem + (size_t)c * HWN + (size_t)y * WW + x0;
  float* orow = out + (size_t)c * HWN + (size_t)y * WW + x0;
#pragma unroll
  for (int sx = 0; sx < 16; sx++) orow[sx] = mrow[sx] + acc[sx];
}

// ---------------- host ----------------
extern "C" void kernel_launch(void* const* d_in, const int* in_sizes, int n_in,
                              void* d_out, int out_size, void* d_ws, size_t ws_size,
                              hipStream_t stream) {
  const float* key     = (const float*)d_in[0];
  const float* beta    = (const float*)d_in[1];
  const float* gate    = (const float*)d_in[2];
  const float* shift   = (const float*)d_in[3];
  const float* sharpen = (const float*)d_in[4];
  const float* prev    = (const float*)d_in[5];
  const float* patch   = (const float*)d_in[6];
  const float* mem     = (const float*)d_in[7];
  float* out = (float*)d_out;

  // scratch layout in d_ws (floats): wfin[HWN], red[9216], scal[16], skb[32]
  float* ws   = (float*)d_ws;
  float* wfin = ws;
  float* red  = ws + HWN;
  float* scal = ws + HWN + 9216;
  float* skb  = ws + HWN + 9216 + 16;

  // HW-sized temporaries live in d_out (dead before k_conv17 rewrites it)
  float* sbuf = out;          // scores, then exp values (in place)
  float* wgb  = out + HWN;    // gated weights

  const int NB = 2048, NT = 256;

  k_score<<<NB, NT, 0, stream>>>(mem, key, beta, sbuf, red);
  k_redmax<<<1, 256, 0, stream>>>(red, scal, shift, skb);
  k_exp<<<NB, NT, 0, stream>>>(sbuf, scal, red);
  k_redsum<<<1, 256, 0, stream>>>(red, scal, 2048, 1);
  k_wg<<<NB, NT, 0, stream>>>(sbuf, prev, scal, gate, wgb);
  dim3 g2(96, 96);
  k_shift<<<g2, 256, 0, stream>>>(wgb, skb, sharpen, wfin, red);
  k_redsum<<<1, 256, 0, stream>>>(red, scal, 9216, 2);
  k_conv17<<<g2, 256, 0, stream>>>(wfin, scal, patch, mem, out);
}

// Round 3
// 230.766 us; speedup vs baseline: 1.9669x; 1.9669x over previous
//
#include <hip/hip_runtime.h>
#include <math.h>

#define HH 1536
#define WW 1536
#define HWN (HH*WW)
#define CC 16
#define KSZ 5
#define PS 17
#define ISTR 88          // LDS column stride (elements); mult-of-8 -> 16B aligned cols
#define NMF 13           // MFMAs per tile: K = 17*24 = 408 -> 13 x K32

typedef __bf16 bf16x8 __attribute__((ext_vector_type(8)));
typedef float f32x4 __attribute__((ext_vector_type(4)));

union Frag { uint4 u4; bf16x8 b8; };

__device__ inline unsigned short f32_to_bf16(float v) {
  unsigned int b = __float_as_uint(v);
  unsigned int r = (b + 0x7FFFu + ((b >> 16) & 1u)) >> 16;
  return (unsigned short)r;
}

// ---------------- reduction helpers ----------------
__device__ inline float waveMax(float v) {
#pragma unroll
  for (int o = 32; o; o >>= 1) v = fmaxf(v, __shfl_xor(v, o));
  return v;
}
__device__ inline float waveSum(float v) {
#pragma unroll
  for (int o = 32; o; o >>= 1) v += __shfl_xor(v, o);
  return v;
}

__device__ inline float softplusf(float x) {
  return x > 20.f ? x : log1pf(expf(x));
}

// ---------------- K1: content score s = beta_pos * cos_sim ----------------
__global__ void k_score(const float* __restrict__ mem, const float* __restrict__ key,
                        const float* __restrict__ beta, float* __restrict__ sbuf,
                        float* __restrict__ red) {
  __shared__ float sm[4];
  float kv[CC];
  float kn = 0.f;
#pragma unroll
  for (int c = 0; c < CC; c++) { kv[c] = key[c]; kn += kv[c] * kv[c]; }
  kn = fmaxf(sqrtf(kn), 1e-8f);
  float scale = softplusf(beta[0]) / kn;

  float lmax = -INFINITY;
  int stride = gridDim.x * blockDim.x;
  for (int hw = blockIdx.x * blockDim.x + threadIdx.x; hw < HWN; hw += stride) {
    float dot = 0.f, nrm = 0.f;
#pragma unroll
    for (int c = 0; c < CC; c++) {
      float m = mem[c * HWN + hw];
      dot += m * kv[c];
      nrm += m * m;
    }
    float s = scale * dot / fmaxf(sqrtf(nrm), 1e-8f);
    sbuf[hw] = s;
    lmax = fmaxf(lmax, s);
  }
  lmax = waveMax(lmax);
  if ((threadIdx.x & 63) == 0) sm[threadIdx.x >> 6] = lmax;
  __syncthreads();
  if (threadIdx.x == 0) {
    float m = sm[0];
    for (int i = 1; i < 4; i++) m = fmaxf(m, sm[i]);
    red[blockIdx.x] = m;
  }
}

// ---------------- K2: reduce max over 2048 partials; shift-kernel softmax ----------------
__global__ void k_redmax(const float* __restrict__ red, float* __restrict__ scal,
                         const float* __restrict__ shift, float* __restrict__ skb) {
  __shared__ float sm[256];
  float m = -INFINITY;
  for (int i = threadIdx.x; i < 2048; i += 256) m = fmaxf(m, red[i]);
  sm[threadIdx.x] = m;
  __syncthreads();
  for (int s = 128; s; s >>= 1) {
    if (threadIdx.x < s) sm[threadIdx.x] = fmaxf(sm[threadIdx.x], sm[threadIdx.x + s]);
    __syncthreads();
  }
  if (threadIdx.x == 0) {
    scal[0] = sm[0];
    float mx = -INFINITY;
    for (int i = 0; i < KSZ * KSZ; i++) mx = fmaxf(mx, shift[i]);
    float e[KSZ * KSZ];
    float sum = 0.f;
    for (int i = 0; i < KSZ * KSZ; i++) { e[i] = expf(shift[i] - mx); sum += e[i]; }
    for (int i = 0; i < KSZ * KSZ; i++) skb[i] = e[i] / sum;
  }
}

// ---------------- K3: e = exp(s - M), partial sums ----------------
__global__ void k_exp(float* __restrict__ sbuf, const float* __restrict__ scal,
                      float* __restrict__ red) {
  __shared__ float sm[4];
  float M = scal[0];
  float lsum = 0.f;
  int stride = gridDim.x * blockDim.x;
  for (int hw = blockIdx.x * blockDim.x + threadIdx.x; hw < HWN; hw += stride) {
    float e = expf(sbuf[hw] - M);
    sbuf[hw] = e;
    lsum += e;
  }
  lsum = waveSum(lsum);
  if ((threadIdx.x & 63) == 0) sm[threadIdx.x >> 6] = lsum;
  __syncthreads();
  if (threadIdx.x == 0) red[blockIdx.x] = sm[0] + sm[1] + sm[2] + sm[3];
}

// ---------------- K4: reduce sum over partials ----------------
__global__ void k_redsum(const float* __restrict__ red, float* __restrict__ scal,
                         int n, int slot) {
  __shared__ float sm[256];
  float s = 0.f;
  for (int i = threadIdx.x; i < n; i += 256) s += red[i];
  sm[threadIdx.x] = s;
  __syncthreads();
  for (int st = 128; st; st >>= 1) {
    if (threadIdx.x < st) sm[threadIdx.x] += sm[threadIdx.x + st];
    __syncthreads();
  }
  if (threadIdx.x == 0) {
    if (slot == 1) scal[1] = sm[0];
    else scal[2] = 1.f / fmaxf(sm[0], 1e-6f);   // invS2 for final normalization
  }
}

// ---------------- K5: w_g = g*e/S + (1-g)*prev ----------------
__global__ void k_wg(const float* __restrict__ e, const float* __restrict__ prev,
                     const float* __restrict__ scal, const float* __restrict__ gate,
                     float* __restrict__ wg) {
  float invS = 1.f / scal[1];
  float g = 1.f / (1.f + expf(-gate[0]));
  float og = 1.f - g;
  int stride = gridDim.x * blockDim.x;
  for (int hw = blockIdx.x * blockDim.x + threadIdx.x; hw < HWN; hw += stride) {
    wg[hw] = g * e[hw] * invS + og * prev[hw];
  }
}

// ---------------- K6: 5x5 circular conv + pow(zeta), partial sums ----------------
__global__ void k_shift(const float* __restrict__ wg, const float* __restrict__ skb,
                        const float* __restrict__ sharpen, float* __restrict__ t,
                        float* __restrict__ red) {
  __shared__ float tile[20][21];
  __shared__ float sks[KSZ * KSZ];
  __shared__ float sm[4];
  int tx = threadIdx.x & 15, ty = threadIdx.x >> 4;
  int x0 = blockIdx.x * 16, y0 = blockIdx.y * 16;
  if (threadIdx.x < KSZ * KSZ) sks[threadIdx.x] = skb[threadIdx.x];
  for (int i = threadIdx.x; i < 400; i += 256) {
    int r = i / 20, c = i % 20;
    int gy = (y0 + r - 2 + HH) % HH;
    int gx = (x0 + c - 2 + WW) % WW;
    tile[r][c] = wg[gy * WW + gx];
  }
  __syncthreads();
  float zeta = softplusf(sharpen[0]) + 1.f;
  float acc = 0.f;
#pragma unroll
  for (int i = 0; i < KSZ; i++)
#pragma unroll
    for (int j = 0; j < KSZ; j++)
      acc += sks[i * KSZ + j] * tile[ty + i][tx + j];
  float tp = powf(fmaxf(acc, 1e-8f), zeta);
  t[(y0 + ty) * WW + x0 + tx] = tp;
  float lsum = waveSum(tp);
  if ((threadIdx.x & 63) == 0) sm[threadIdx.x >> 6] = lsum;
  __syncthreads();
  if (threadIdx.x == 0) red[blockIdx.y * 96 + blockIdx.x] = sm[0] + sm[1] + sm[2] + sm[3];
}

// ---------------- K7: prebuild patch A-fragments (tile-invariant) ----------------
// Layout: afrag[((mf*4 + hi)*16 + c)*8 + j]  (bf16), 16B-aligned per (mf,hi,c).
// k = mf*32 + hi*8 + j ; u' = k % 24 ; v = k / 24 ; u = 23 - u'.
// value = patch[c][u][v] if (u <= 16 && v <= 16) else 0.
__global__ void k_afrag(const float* __restrict__ patch, unsigned short* __restrict__ afrag) {
  int idx = blockIdx.x * 256 + threadIdx.x;
  if (idx >= NMF * 4 * 16 * 8) return;
  int j = idx & 7;
  int c = (idx >> 3) & 15;
  int hi = (idx >> 7) & 3;
  int mf = idx >> 9;
  int k = mf * 32 + hi * 8 + j;
  int up = k % 24;
  int v = k / 24;
  int u = 23 - up;
  float val = 0.f;
  if (u <= 16 && v <= 16) val = patch[(c * PS + u) * PS + v];
  afrag[idx] = f32_to_bf16(val);
}

// ---------------- K8: 17x17 true conv via MFMA + mem add ----------------
// Block (bx, by, r): x0 = 16*bx; 8 y-tiles y = 64*by + r + 8*t, t=0..7.
// LDS: column-major bf16 field ca[X][i], X in [0,32) -> x = x0 - 8 + X,
//      i in [0,80) -> row = yBase + i, yBase = 64*by + r - 15.
// B-fragment for (tile t, mf, hi): lane l (col=l&15):
//   v = (mf*32+hi*8)/24, u'0 = (mf*32+hi*8)%24, X = col + 16 - v,
//   elem j at ca[X*ISTR + 8*t + u'0 + j]  (contiguous, 16B aligned).
__global__ void __launch_bounds__(256) k_conv17m(
    const float* __restrict__ t, const float* __restrict__ scal,
    const unsigned short* __restrict__ afrag, const float* __restrict__ mem,
    float* __restrict__ out) {
  __shared__ unsigned short ca[32 * ISTR];
  int tid = threadIdx.x;
  int x0 = blockIdx.x * 16;
  int yBase = blockIdx.y * 64 + blockIdx.z - 15;
  float invS = scal[2];

  // stage 32 x 80 window, zero-padded at image borders, pre-scaled by invS
  for (int idx = tid; idx < 32 * 80; idx += 256) {
    int X = idx & 31, i = idx >> 5;
    int x = x0 - 8 + X;
    int y = yBase + i;
    float v = 0.f;
    if (x >= 0 && x < WW && y >= 0 && y < HH) v = t[y * WW + x] * invS;
    ca[X * ISTR + i] = f32_to_bf16(v);
  }
  __syncthreads();

  int lane = tid & 63;
  int w = tid >> 6;
  int col = lane & 15, hi = lane >> 4;

  // load A fragments (patch), shared by all tiles
  Frag A[NMF];
#pragma unroll
  for (int mf = 0; mf < NMF; mf++) {
    A[mf].u4 = *reinterpret_cast<const uint4*>(afrag + ((mf * 4 + hi) * 16 + col) * 8);
  }

#pragma unroll 1
  for (int tt = 0; tt < 2; tt++) {
    int tIdx = w * 2 + tt;
    int y = blockIdx.y * 64 + blockIdx.z + 8 * tIdx;
    f32x4 acc = {0.f, 0.f, 0.f, 0.f};
#pragma unroll
    for (int mf = 0; mf < NMF; mf++) {
      int k0 = mf * 32 + hi * 8;
      int u0 = k0 % 24;
      int v = k0 / 24;
      int X = col + 16 - v;
      int base = X * ISTR + 8 * tIdx + u0;
      if (base < 0) base = 0;   // v==17 zero-pad octet; A is 0 there
      Frag B;
      B.u4 = *reinterpret_cast<const uint4*>(ca + base);
      acc = __builtin_amdgcn_mfma_f32_16x16x32_bf16(A[mf].b8, B.b8, acc, 0, 0, 0);
    }
    // epilogue: out[c][y][x0+col] = mem + acc, c = hi*4 + reg
    int xo = x0 + col;
#pragma unroll
    for (int reg = 0; reg < 4; reg++) {
      int c = hi * 4 + reg;
      size_t off = (size_t)c * HWN + (size_t)y * WW + xo;
      out[off] = mem[off] + acc[reg];
    }
  }
}

// ---------------- host ----------------
extern "C" void kernel_launch(void* const* d_in, const int* in_sizes, int n_in,
                              void* d_out, int out_size, void* d_ws, size_t ws_size,
                              hipStream_t stream) {
  const float* key     = (const float*)d_in[0];
  const float* beta    = (const float*)d_in[1];
  const float* gate    = (const float*)d_in[2];
  const float* shift   = (const float*)d_in[3];
  const float* sharpen = (const float*)d_in[4];
  const float* prev    = (const float*)d_in[5];
  const float* patch   = (const float*)d_in[6];
  const float* mem     = (const float*)d_in[7];
  float* out = (float*)d_out;

  // scratch layout in d_ws (floats): wfin[HWN], red[9216], scal[16], skb[32], afrag
  float* ws   = (float*)d_ws;
  float* wfin = ws;
  float* red  = ws + HWN;
  float* scal = ws + HWN + 9216;
  float* skb  = ws + HWN + 9216 + 16;
  unsigned short* afrag = (unsigned short*)(ws + HWN + 9216 + 16 + 32);

  // HW-sized temporaries live in d_out (dead before k_conv17m rewrites it)
  float* sbuf = out;          // scores, then exp values (in place)
  float* wgb  = out + HWN;    // gated weights

  const int NB = 2048, NT = 256;

  k_afrag<<<26, 256, 0, stream>>>(patch, afrag);
  k_score<<<NB, NT, 0, stream>>>(mem, key, beta, sbuf, red);
  k_redmax<<<1, 256, 0, stream>>>(red, scal, shift, skb);
  k_exp<<<NB, NT, 0, stream>>>(sbuf, scal, red);
  k_redsum<<<1, 256, 0, stream>>>(red, scal, 2048, 1);
  k_wg<<<NB, NT, 0, stream>>>(sbuf, prev, scal, gate, wgb);
  dim3 g2(96, 96);
  k_shift<<<g2, 256, 0, stream>>>(wgb, skb, sharpen, wfin, red);
  k_redsum<<<1, 256, 0, stream>>>(red, scal, 9216, 2);
  dim3 g3(96, 24, 8);
  k_conv17m<<<g3, 256, 0, stream>>>(wfin, scal, afrag, mem, out);
}

// Round 4
// 184.456 us; speedup vs baseline: 2.4608x; 1.2511x over previous
//
#include <hip/hip_runtime.h>
#include <math.h>

#define HH 1536
#define WW 1536
#define HWN (HH*WW)
#define CC 16
#define KSZ 5
#define PS 17
#define ISTR 88          // LDS column stride (elements); mult-of-8 -> 16B aligned octets
#define NMF 13           // MFMAs per tile: K = 17*24 = 408 -> 13 x K32

typedef __bf16 bf16x8 __attribute__((ext_vector_type(8)));
typedef float f32x4 __attribute__((ext_vector_type(4)));

union Frag { uint4 u4; bf16x8 b8; };

__device__ inline unsigned short f32_to_bf16(float v) {
  unsigned int b = __float_as_uint(v);
  unsigned int r = (b + 0x7FFFu + ((b >> 16) & 1u)) >> 16;
  return (unsigned short)r;
}

__device__ inline float softplusf(float x) {
  return x > 20.f ? x : log1pf(expf(x));
}

__device__ inline float waveSum(float v) {
#pragma unroll
  for (int o = 32; o; o >>= 1) v += __shfl_xor(v, o);
  return v;
}

// ---------------- K1: fused content score + exp (M = beta_pos bound) ----------------
// s = beta_pos * cossim <= beta_pos, so e = exp(s - beta_pos) <= 1. Softmax is
// shift-invariant, so any M works; this removes the global-max pass entirely.
__global__ void k_scoreexp(const float* __restrict__ mem, const float* __restrict__ key,
                           const float* __restrict__ beta, float* __restrict__ e,
                           float* __restrict__ red) {
  __shared__ float sm[4];
  float kv[CC];
  float kn = 0.f;
#pragma unroll
  for (int c = 0; c < CC; c++) { kv[c] = key[c]; kn += kv[c] * kv[c]; }
  float bp = softplusf(beta[0]);
  float scale = bp / fmaxf(sqrtf(kn), 1e-8f);

  int hw4 = (blockIdx.x * 256 + threadIdx.x) * 4;
  float d0 = 0.f, d1 = 0.f, d2 = 0.f, d3 = 0.f;
  float n0 = 0.f, n1 = 0.f, n2 = 0.f, n3 = 0.f;
#pragma unroll
  for (int c = 0; c < CC; c++) {
    float4 m = *reinterpret_cast<const float4*>(mem + (size_t)c * HWN + hw4);
    d0 += m.x * kv[c]; d1 += m.y * kv[c]; d2 += m.z * kv[c]; d3 += m.w * kv[c];
    n0 += m.x * m.x;   n1 += m.y * m.y;   n2 += m.z * m.z;   n3 += m.w * m.w;
  }
  float4 ev;
  ev.x = expf(scale * d0 / fmaxf(sqrtf(n0), 1e-8f) - bp);
  ev.y = expf(scale * d1 / fmaxf(sqrtf(n1), 1e-8f) - bp);
  ev.z = expf(scale * d2 / fmaxf(sqrtf(n2), 1e-8f) - bp);
  ev.w = expf(scale * d3 / fmaxf(sqrtf(n3), 1e-8f) - bp);
  *reinterpret_cast<float4*>(e + hw4) = ev;

  float lsum = waveSum(ev.x + ev.y + ev.z + ev.w);
  if ((threadIdx.x & 63) == 0) sm[threadIdx.x >> 6] = lsum;
  __syncthreads();
  if (threadIdx.x == 0) red[blockIdx.x] = sm[0] + sm[1] + sm[2] + sm[3];
}

// ---------------- K2: reduce S = sum(e); gate scalars; shift-kernel softmax ----------------
__global__ void k_mid1(const float* __restrict__ red, float* __restrict__ scal,
                       const float* __restrict__ shift, float* __restrict__ skb,
                       const float* __restrict__ gate) {
  __shared__ float sm[256];
  float s = 0.f;
  for (int i = threadIdx.x; i < 2304; i += 256) s += red[i];
  sm[threadIdx.x] = s;
  __syncthreads();
  for (int st = 128; st; st >>= 1) {
    if (threadIdx.x < st) sm[threadIdx.x] += sm[threadIdx.x + st];
    __syncthreads();
  }
  if (threadIdx.x == 0) {
    float S = sm[0];
    float g = 1.f / (1.f + expf(-gate[0]));
    scal[3] = g / S;       // g * w_c = (g/S) * e
    scal[4] = 1.f - g;
    float mx = -INFINITY;
    for (int i = 0; i < KSZ * KSZ; i++) mx = fmaxf(mx, shift[i]);
    float ee[KSZ * KSZ];
    float sum = 0.f;
    for (int i = 0; i < KSZ * KSZ; i++) { ee[i] = expf(shift[i] - mx); sum += ee[i]; }
    for (int i = 0; i < KSZ * KSZ; i++) skb[i] = ee[i] / sum;
  }
}

// ---------------- K3: fused wg + 5x5 circular conv + pow(zeta) -> bf16 t, partial sums ----
__global__ void k_shiftf(const float* __restrict__ e, const float* __restrict__ prev,
                         const float* __restrict__ scal, const float* __restrict__ skb,
                         const float* __restrict__ sharpen, unsigned short* __restrict__ tbf,
                         float* __restrict__ red) {
  __shared__ float tile[20][21];
  __shared__ float sks[KSZ * KSZ];
  __shared__ float sm[4];
  int tx = threadIdx.x & 15, ty = threadIdx.x >> 4;
  int x0 = blockIdx.x * 16, y0 = blockIdx.y * 16;
  if (threadIdx.x < KSZ * KSZ) sks[threadIdx.x] = skb[threadIdx.x];
  float gS = scal[3], og = scal[4];
  for (int i = threadIdx.x; i < 400; i += 256) {
    int r = i / 20, c = i % 20;
    int gy = (y0 + r - 2 + HH) % HH;
    int gx = (x0 + c - 2 + WW) % WW;
    int idx = gy * WW + gx;
    tile[r][c] = gS * e[idx] + og * prev[idx];
  }
  __syncthreads();
  float zeta = softplusf(sharpen[0]) + 1.f;
  float acc = 0.f;
#pragma unroll
  for (int i = 0; i < KSZ; i++)
#pragma unroll
    for (int j = 0; j < KSZ; j++)
      acc += sks[i * KSZ + j] * tile[ty + i][tx + j];
  float tp = powf(fmaxf(acc, 1e-8f), zeta);
  tbf[(y0 + ty) * WW + x0 + tx] = f32_to_bf16(tp);
  float lsum = waveSum(tp);
  if ((threadIdx.x & 63) == 0) sm[threadIdx.x >> 6] = lsum;
  __syncthreads();
  if (threadIdx.x == 0) red[blockIdx.y * 96 + blockIdx.x] = sm[0] + sm[1] + sm[2] + sm[3];
}

// ---------------- K4: reduce S2; build A-fragments scaled by 1/S2 ----------------
// Layout: afrag[((mf*4 + hi)*16 + c)*8 + j]  (bf16).
// k = mf*32 + hi*8 + j ; u' = k % 24 ; v = k / 24 ; u = 23 - u'.
__global__ void k_mid2(const float* __restrict__ red, float* __restrict__ scal,
                       const float* __restrict__ patch, unsigned short* __restrict__ afrag) {
  __shared__ float sm[256];
  __shared__ float sInv;
  float s = 0.f;
  for (int i = threadIdx.x; i < 9216; i += 256) s += red[i];
  sm[threadIdx.x] = s;
  __syncthreads();
  for (int st = 128; st; st >>= 1) {
    if (threadIdx.x < st) sm[threadIdx.x] += sm[threadIdx.x + st];
    __syncthreads();
  }
  if (threadIdx.x == 0) { sInv = 1.f / fmaxf(sm[0], 1e-6f); scal[2] = sInv; }
  __syncthreads();
  float invS = sInv;
  for (int idx = threadIdx.x; idx < NMF * 4 * 16 * 8; idx += 256) {
    int j = idx & 7;
    int c = (idx >> 3) & 15;
    int hi = (idx >> 7) & 3;
    int mf = idx >> 9;
    int k = mf * 32 + hi * 8 + j;
    int up = k % 24;
    int v = k / 24;
    int u = 23 - up;
    float val = 0.f;
    if (u <= 16 && v <= 16) val = patch[(c * PS + u) * PS + v] * invS;
    afrag[idx] = f32_to_bf16(val);
  }
}

// ---------------- K5: 17x17 true conv via MFMA + mem add ----------------
// Block (bx, by, z): x0 = 16*bx; 8 y-rows y = 64*by + z + 8*t, t=0..7.
// LDS: column-major bf16 field ca[X][i], X in [0,32) -> x = x0 - 8 + X,
//      i in [0,80) -> row = yBase + i, yBase = 64*by + z - 15.
// Staging: one ds_write_b128 per (X, i-octet) from 8 coalesced ushort loads.
// B-fragment (tile t, mf, hi), lane col: v=k0/24, u0=k0%24, X=col+16-v,
//   16B read at ca[X*ISTR + 8t + u0]  (16B aligned since ISTR%8==0, u0 in {0,8,16}).
__global__ void __launch_bounds__(256) k_conv17m(
    const unsigned short* __restrict__ tbf, const unsigned short* __restrict__ afrag,
    const float* __restrict__ mem, float* __restrict__ out) {
  __shared__ __align__(16) unsigned short ca[32 * ISTR];
  int tid = threadIdx.x;
  int x0 = blockIdx.x * 16;
  int yBase = blockIdx.y * 64 + blockIdx.z - 15;

  // stage 32 X-columns x 80 rows as 320 b128 writes (column-major, conflict-light)
  for (int idx = tid; idx < 320; idx += 256) {
    int X = idx & 31, oct = idx >> 5;
    int x = x0 - 8 + X;
    bool xok = (x >= 0) && (x < WW);
    int yb = yBase + oct * 8;
    unsigned short v[8];
#pragma unroll
    for (int j = 0; j < 8; j++) {
      int y = yb + j;
      v[j] = (xok && y >= 0 && y < HH) ? tbf[y * WW + x] : (unsigned short)0;
    }
    uint4 q;
    q.x = (unsigned)v[0] | ((unsigned)v[1] << 16);
    q.y = (unsigned)v[2] | ((unsigned)v[3] << 16);
    q.z = (unsigned)v[4] | ((unsigned)v[5] << 16);
    q.w = (unsigned)v[6] | ((unsigned)v[7] << 16);
    *reinterpret_cast<uint4*>(ca + X * ISTR + oct * 8) = q;
  }
  __syncthreads();

  int lane = tid & 63;
  int w = tid >> 6;
  int col = lane & 15, hi = lane >> 4;

  // A fragments (patch * invS), shared by all tiles
  Frag A[NMF];
#pragma unroll
  for (int mf = 0; mf < NMF; mf++) {
    A[mf].u4 = *reinterpret_cast<const uint4*>(afrag + ((mf * 4 + hi) * 16 + col) * 8);
  }

#pragma unroll 1
  for (int tt = 0; tt < 2; tt++) {
    int tIdx = w * 2 + tt;
    int y = blockIdx.y * 64 + blockIdx.z + 8 * tIdx;
    f32x4 acc = {0.f, 0.f, 0.f, 0.f};
#pragma unroll
    for (int mf = 0; mf < NMF; mf++) {
      int k0 = mf * 32 + hi * 8;
      int u0 = k0 % 24;
      int v = k0 / 24;
      int X = col + 16 - v;
      int base = X * ISTR + 8 * tIdx + u0;
      if (base < 0) base = 0;   // v==17 zero-pad octet; A is 0 there
      Frag B;
      B.u4 = *reinterpret_cast<const uint4*>(ca + base);
      acc = __builtin_amdgcn_mfma_f32_16x16x32_bf16(A[mf].b8, B.b8, acc, 0, 0, 0);
    }
    // epilogue: out[c][y][x0+col] = mem + acc, c = hi*4 + reg (invS already in A)
    int xo = x0 + col;
#pragma unroll
    for (int reg = 0; reg < 4; reg++) {
      int c = hi * 4 + reg;
      size_t off = (size_t)c * HWN + (size_t)y * WW + xo;
      out[off] = mem[off] + acc[reg];
    }
  }
}

// ---------------- host ----------------
extern "C" void kernel_launch(void* const* d_in, const int* in_sizes, int n_in,
                              void* d_out, int out_size, void* d_ws, size_t ws_size,
                              hipStream_t stream) {
  const float* key     = (const float*)d_in[0];
  const float* beta    = (const float*)d_in[1];
  const float* gate    = (const float*)d_in[2];
  const float* shift   = (const float*)d_in[3];
  const float* sharpen = (const float*)d_in[4];
  const float* prev    = (const float*)d_in[5];
  const float* patch   = (const float*)d_in[6];
  const float* mem     = (const float*)d_in[7];
  float* out = (float*)d_out;

  // ws layout: tbf ushort[HWN] | red f32[9216] | scal f32[16] | skb f32[32] | afrag ushort[6656]
  float* ws = (float*)d_ws;
  unsigned short* tbf = (unsigned short*)ws;
  float* red  = ws + HWN / 2;
  float* scal = red + 9216;
  float* skb  = scal + 16;
  unsigned short* afrag = (unsigned short*)(skb + 32);

  // e lives in d_out (dead before k_conv17m rewrites it)
  float* e = out;

  k_scoreexp<<<2304, 256, 0, stream>>>(mem, key, beta, e, red);
  k_mid1<<<1, 256, 0, stream>>>(red, scal, shift, skb, gate);
  dim3 g2(96, 96);
  k_shiftf<<<g2, 256, 0, stream>>>(e, prev, scal, skb, sharpen, tbf, red);
  k_mid2<<<1, 256, 0, stream>>>(red, scal, patch, afrag);
  dim3 g3(96, 24, 8);
  k_conv17m<<<g3, 256, 0, stream>>>(tbf, afrag, mem, out);
}